// Round 4
// baseline (1014.622 us; speedup 1.0000x reference)
//
#include <hip/hip_runtime.h>
#include <math.h>

#define NB 32
#define NN 3136
#define CD 320
#define NH 5
#define CN 400
#define NKEY 196
#define DQ 80
#define DV 64
#define SCALE_F 0.11180339887498949f

#define STD 332  // dwc_s row stride (u16)
#define STX 420  // xs_s row stride
#define STQ 420  // q_s row stride
#define STP 68   // P chunk row stride

typedef __bf16 bf16x8 __attribute__((ext_vector_type(8)));
typedef float f32x4 __attribute__((ext_vector_type(4)));
typedef unsigned short u16;
typedef unsigned int u32;

__device__ __forceinline__ u16 f2bf(float f) {
  u32 u = __float_as_uint(f);
  u += 0x7fffu + ((u >> 16) & 1u);  // round-to-nearest-even
  return (u16)(u >> 16);
}

__device__ __forceinline__ bf16x8 pack8(const float4 a, const float4 b) {
  union { bf16x8 v; u16 s[8]; } u;
  u.s[0] = f2bf(a.x); u.s[1] = f2bf(a.y); u.s[2] = f2bf(a.z); u.s[3] = f2bf(a.w);
  u.s[4] = f2bf(b.x); u.s[5] = f2bf(b.y); u.s[6] = f2bf(b.z); u.s[7] = f2bf(b.w);
  return u.v;
}

#define MFMA(a, b, c) __builtin_amdgcn_mfma_f32_16x16x32_bf16((a), (b), (c), 0, 0, 0)

// ---------------------------------------------------------------------------
// Prep: qwT [400][320] = q_w^T; pwT [320][320] = proj_w^T;
// kvwT [720][416] (k_w^T ++ v_w^T, k-cols 400..415 zero); pwc [400][320] = pw_w.
// ---------------------------------------------------------------------------
__global__ void k_prep(const float* __restrict__ q_w,
                       const float* __restrict__ proj_w,
                       const float* __restrict__ k_w,
                       const float* __restrict__ v_w,
                       const float* __restrict__ pw_w, u16* __restrict__ qwT,
                       u16* __restrict__ pwT, u16* __restrict__ kvwT,
                       u16* __restrict__ pwc) {
  const int i0 = blockIdx.x * 256 + threadIdx.x;
  const int stride = gridDim.x * 256;
  for (int idx = i0; idx < 400 * 320; idx += stride) {
    const int o = idx / 320, c = idx - o * 320;
    qwT[idx] = f2bf(q_w[(size_t)c * 400 + o]);
    pwc[idx] = f2bf(pw_w[idx]);
  }
  for (int idx = i0; idx < 320 * 320; idx += stride) {
    const int o = idx / 320, c = idx - o * 320;
    pwT[idx] = f2bf(proj_w[(size_t)c * 320 + o]);
  }
  for (int idx = i0; idx < 720 * 416; idx += stride) {
    const int o = idx / 416, c = idx - o * 416;
    float v = 0.f;
    if (c < 400)
      v = (o < 400) ? k_w[(size_t)c * 400 + o] : v_w[(size_t)c * 320 + (o - 400)];
    kvwT[idx] = f2bf(v);
  }
}

// ---------------------------------------------------------------------------
// Kernel 1 (single-wave blocks, barrier-free): per 16 keys of one batch:
// dwconv -> bf16 LDS -> MFMA pointwise (+bias) -> register LN + GELU ->
// bf16 LDS -> MFMA K/V GEMM -> kbp [6288][480] (head-padded) + vt [32*320][224].
// grid (13, 32), block 64.
// ---------------------------------------------------------------------------
__global__ __launch_bounds__(64) void k_spkv(
    const float* __restrict__ x, const float* __restrict__ dw_w,
    const float* __restrict__ dw_b, const u16* __restrict__ pwc,
    const float* __restrict__ pw_b, const float* __restrict__ ln_g,
    const float* __restrict__ ln_b, const u16* __restrict__ kvwT,
    u16* __restrict__ kbp, u16* __restrict__ vt) {
  const int kt = blockIdx.x, b = blockIdx.y;
  const int lane = threadIdx.x;
  const int quad = lane >> 4, l15 = lane & 15;
  const int key0 = kt * 16;
  const f32x4 fz = {0.f, 0.f, 0.f, 0.f};

  __shared__ u16 dwc_s[16 * STD];
  __shared__ u16 xs_s[16 * STX];

  // ---- depthwise conv: 16 keys x 320 channels (tail keys -> 0)
  const float* xb = x + (size_t)b * NN * CD;
#pragma unroll 1
  for (int t = 0; t < 80; t++) {
    const int idx = t * 64 + lane;
    const int kk = idx / 320, c = idx - kk * 320;
    const int key = key0 + kk;
    float acc = 0.f;
    if (key < NKEY) {
      const int oh = key / 14, ow = key - oh * 14;
      acc = dw_b[c];
#pragma unroll
      for (int i = 0; i < 4; i++)
#pragma unroll
        for (int j = 0; j < 4; j++)
          acc += xb[(size_t)((oh * 4 + i) * 56 + ow * 4 + j) * CD + c] *
                 dw_w[c * 16 + i * 4 + j];
    }
    dwc_s[kk * STD + c] = f2bf(acc);
  }

  // ---- pointwise 320 -> 400 via MFMA, bias, LN, GELU (all in C-layout regs)
  f32x4 acc[25];
#pragma unroll
  for (int n = 0; n < 25; n++) acc[n] = fz;
  {
    bf16x8 A[10];
#pragma unroll
    for (int ks = 0; ks < 10; ks++)
      A[ks] = *(const bf16x8*)(dwc_s + l15 * STD + ks * 32 + quad * 8);
#pragma unroll
    for (int n = 0; n < 25; n++) {
      const u16* wr = pwc + (size_t)(n * 16 + l15) * CD;
#pragma unroll
      for (int ks = 0; ks < 10; ks++) {
        const bf16x8 B = *(const bf16x8*)(wr + ks * 32 + quad * 8);
        acc[n] = MFMA(A[ks], B, acc[n]);
      }
    }
  }
#pragma unroll
  for (int n = 0; n < 25; n++) {
    const float pb = pw_b[n * 16 + l15];
#pragma unroll
    for (int r = 0; r < 4; r++) acc[n][r] += pb;
  }
  // LN stats per row (row = quad*4+r; cols spread over n regs x l15 lanes)
  {
    float s1[4] = {0, 0, 0, 0}, s2[4] = {0, 0, 0, 0};
#pragma unroll
    for (int n = 0; n < 25; n++)
#pragma unroll
      for (int r = 0; r < 4; r++) {
        s1[r] += acc[n][r];
        s2[r] += acc[n][r] * acc[n][r];
      }
#pragma unroll
    for (int r = 0; r < 4; r++) {
      s1[r] += __shfl_xor(s1[r], 1); s2[r] += __shfl_xor(s2[r], 1);
      s1[r] += __shfl_xor(s1[r], 2); s2[r] += __shfl_xor(s2[r], 2);
      s1[r] += __shfl_xor(s1[r], 4); s2[r] += __shfl_xor(s2[r], 4);
      s1[r] += __shfl_xor(s1[r], 8); s2[r] += __shfl_xor(s2[r], 8);
      const float mu = s1[r] * (1.f / 400.f);
      const float var = s2[r] * (1.f / 400.f) - mu * mu;
      const float rstd = rsqrtf(var + 1e-5f);
      s1[r] = mu;
      s2[r] = rstd;
    }
#pragma unroll
    for (int n = 0; n < 25; n++) {
      const float g = ln_g[n * 16 + l15], be = ln_b[n * 16 + l15];
#pragma unroll
      for (int r = 0; r < 4; r++) {
        const float v = (acc[n][r] - s1[r]) * s2[r] * g + be;
        const float ge = 0.5f * v * (1.f + erff(v * 0.70710678118654752f));
        xs_s[(quad * 4 + r) * STX + n * 16 + l15] = f2bf(ge);
      }
    }
  }
  // zero pad cols 400..419
#pragma unroll
  for (int t = 0; t < 5; t++) {
    const int idx = t * 64 + lane;  // 16 rows x 20 cols
    xs_s[(idx / 20) * STX + 400 + (idx % 20)] = 0;
  }

  // ---- K/V GEMM: [16][416] @ kvwT^T -> kbp (head-padded) + vt (transposed)
  {
    bf16x8 XA[13];
#pragma unroll
    for (int ks = 0; ks < 13; ks++)
      XA[ks] = *(const bf16x8*)(xs_s + l15 * STX + ks * 32 + quad * 8);
#pragma unroll 1
    for (int nt = 0; nt < 45; nt++) {
      f32x4 a2 = fz;
      const u16* wr = kvwT + (size_t)(nt * 16 + l15) * 416;
#pragma unroll
      for (int ks = 0; ks < 13; ks++) {
        const bf16x8 B = *(const bf16x8*)(wr + ks * 32 + quad * 8);
        a2 = MFMA(XA[ks], B, a2);
      }
      const int col = nt * 16 + l15;
      if (col < 400) {
        const int dcol = col + 16 * (col / 80);  // head-padded column
#pragma unroll
        for (int r = 0; r < 4; r++) {
          const int key = key0 + quad * 4 + r;
          if (key < NKEY)
            kbp[(size_t)(b * NKEY + key) * 480 + dcol] = f2bf(a2[r]);
        }
      } else {
        const int vo = col - 400;
#pragma unroll
        for (int r = 0; r < 4; r++) {
          const int key = key0 + quad * 4 + r;
          if (key < NKEY)
            vt[(size_t)(b * CD + vo) * 224 + key] = f2bf(a2[r]);
        }
      }
    }
  }
  // zero-fill kbp per-head pad columns (cols 96h+80..96h+95) for own keys
#pragma unroll 1
  for (int t = 0; t < 20; t++) {
    const int idx = t * 64 + lane;  // 16 rows x 80 pad cols
    const int rr = idx / 80, cc = idx - rr * 80;
    const int key = key0 + rr;
    if (key < NKEY)
      kbp[(size_t)(b * NKEY + key) * 480 + (cc >> 4) * 96 + 80 + (cc & 15)] = 0;
  }
}

// ---------------------------------------------------------------------------
// Kernel 2 (2-wave blocks, barrier-free): per 32 queries of one batch:
// q GEMM (all heads) -> wave-private LDS; per head: S (q LDS A-frags + K
// global B-frags), register softmax (no max-sub), PV in 64-key chunks via
// wave-private P; O overwrites dead q columns; fused out-projection.
// grid (98, 32), block 128. LDS 31232 B -> 5 blocks/CU.
// ---------------------------------------------------------------------------
__global__ __launch_bounds__(128) void k_mega(
    const float* __restrict__ x, const u16* __restrict__ qwT,
    const u16* __restrict__ kbp, const u16* __restrict__ vt,
    const u16* __restrict__ pwT, const float* __restrict__ proj_b,
    float* __restrict__ out) {
  const int qt = blockIdx.x, b = blockIdx.y;
  const int tid = threadIdx.x, lane = tid & 63, wv = tid >> 6;
  const int quad = lane >> 4, l15 = lane & 15;
  const int q0 = qt * 32, m0 = wv * 16;
  const f32x4 fz = {0.f, 0.f, 0.f, 0.f};

  __shared__ u16 q_s[32 * STQ];
  __shared__ u16 Ps[2][16 * STP];
  u16* P = Ps[wv];

  // ---- Phase Q: q[16 rows][400] = x @ q_w (wave-private rows m0..m0+15)
  {
    bf16x8 xA[10];
    const float* xr = x + (size_t)(b * NN + q0 + m0 + l15) * CD;
#pragma unroll
    for (int ks = 0; ks < 10; ks++) {
      const float4 a = *(const float4*)(xr + ks * 32 + quad * 8);
      const float4 bb = *(const float4*)(xr + ks * 32 + quad * 8 + 4);
      xA[ks] = pack8(a, bb);
    }
#pragma unroll 1
    for (int n = 0; n < 25; n++) {
      f32x4 acc = fz;
      const u16* wr = qwT + (size_t)(n * 16 + l15) * CD;
#pragma unroll
      for (int ks = 0; ks < 10; ks++) {
        const bf16x8 B = *(const bf16x8*)(wr + ks * 32 + quad * 8);
        acc = MFMA(xA[ks], B, acc);
      }
#pragma unroll
      for (int r = 0; r < 4; r++)
        q_s[(m0 + quad * 4 + r) * STQ + n * 16 + l15] = f2bf(acc[r]);
    }
    // zero own rows' pad cols 400..419 (covers head-4 frag overread)
#pragma unroll
    for (int t = 0; t < 5; t++) {
      const int idx = t * 64 + lane;  // 16 x 20
      q_s[(m0 + idx / 20) * STQ + 400 + (idx % 20)] = 0;
    }
  }

  // ---- heads
  const u16* kb_b = kbp + (size_t)(b * NKEY) * 480;
  const u16* vt_b = vt + (size_t)(b * CD) * 224;
#pragma unroll 1
  for (int h = 0; h < 5; h++) {
    // S[16][208] = q @ K^T  (k-dim 96: cols 80..95 zero on K side)
    f32x4 sacc[13];
#pragma unroll
    for (int n = 0; n < 13; n++) sacc[n] = fz;
    {
      bf16x8 a[3];
#pragma unroll
      for (int ks = 0; ks < 3; ks++)
        a[ks] = *(const bf16x8*)(q_s + (m0 + l15) * STQ + h * DQ + ks * 32 +
                                 quad * 8);
#pragma unroll
      for (int n = 0; n < 13; n++) {
        const u16* kr = kb_b + (size_t)(n * 16 + l15) * 480 + h * 96;
#pragma unroll
        for (int ks = 0; ks < 3; ks++) {
          const bf16x8 B = *(const bf16x8*)(kr + ks * 32 + quad * 8);
          sacc[n] = MFMA(a[ks], B, sacc[n]);
        }
      }
    }
    // softmax (no max subtraction; |s*scale| is small by construction)
    {
      float sum[4] = {0.f, 0.f, 0.f, 0.f};
#pragma unroll
      for (int n = 0; n < 13; n++)
#pragma unroll
        for (int r = 0; r < 4; r++) {
          const float e =
              (n == 12 && l15 >= 4) ? 0.f : __expf(sacc[n][r] * SCALE_F);
          sacc[n][r] = e;
          sum[r] += e;
        }
#pragma unroll
      for (int r = 0; r < 4; r++) {
        sum[r] += __shfl_xor(sum[r], 1);
        sum[r] += __shfl_xor(sum[r], 2);
        sum[r] += __shfl_xor(sum[r], 4);
        sum[r] += __shfl_xor(sum[r], 8);
        const float inv = 1.f / sum[r];
#pragma unroll
        for (int n = 0; n < 13; n++) sacc[n][r] *= inv;
      }
    }
    // PV in 4 chunks of 64 keys (chunk 3: keys 192..223, only 4 real)
    f32x4 oacc[4];
#pragma unroll
    for (int n = 0; n < 4; n++) oacc[n] = fz;
#pragma unroll 1
    for (int ch = 0; ch < 4; ch++) {
      if (ch < 3) {
#pragma unroll
        for (int nn = 0; nn < 4; nn++) {
          const int n = ch * 4 + nn;
#pragma unroll
          for (int r = 0; r < 4; r++)
            P[(quad * 4 + r) * STP + nn * 16 + l15] = f2bf(sacc[n][r]);
        }
        const bf16x8 pa0 = *(const bf16x8*)(P + l15 * STP + quad * 8);
        const bf16x8 pa1 = *(const bf16x8*)(P + l15 * STP + 32 + quad * 8);
#pragma unroll
        for (int n = 0; n < 4; n++) {
          const u16* vr = vt_b + (size_t)(h * DV + n * 16 + l15) * 224 + ch * 64;
          oacc[n] = MFMA(pa0, *(const bf16x8*)(vr + quad * 8), oacc[n]);
          oacc[n] = MFMA(pa1, *(const bf16x8*)(vr + 32 + quad * 8), oacc[n]);
        }
      } else {
#pragma unroll
        for (int r = 0; r < 4; r++)
          P[(quad * 4 + r) * STP + l15] = f2bf(sacc[12][r]);
        // zero cols 16..31 (keys 208..223)
        {
          const int rr = lane >> 2, cc = lane & 3;
#pragma unroll
          for (int t = 0; t < 4; t++) P[rr * STP + 16 + cc * 4 + t] = 0;
        }
        const bf16x8 pa0 = *(const bf16x8*)(P + l15 * STP + quad * 8);
#pragma unroll
        for (int n = 0; n < 4; n++) {
          const u16* vr = vt_b + (size_t)(h * DV + n * 16 + l15) * 224 + 192;
          oacc[n] = MFMA(pa0, *(const bf16x8*)(vr + quad * 8), oacc[n]);
        }
      }
    }
    // O_h (bf16) overwrites dead q columns [64h, 64h+64)
#pragma unroll
    for (int n = 0; n < 4; n++)
#pragma unroll
      for (int r = 0; r < 4; r++)
        q_s[(m0 + quad * 4 + r) * STQ + h * DV + n * 16 + l15] =
            f2bf(oacc[n][r]);
  }

  // ---- fused projection: out = O @ proj_w + proj_b
  {
    bf16x8 pA[10];
#pragma unroll
    for (int ks = 0; ks < 10; ks++)
      pA[ks] = *(const bf16x8*)(q_s + (m0 + l15) * STQ + ks * 32 + quad * 8);
#pragma unroll 1
    for (int n = 0; n < 20; n++) {
      f32x4 acc = fz;
      const u16* wr = pwT + (size_t)(n * 16 + l15) * CD;
#pragma unroll
      for (int ks = 0; ks < 10; ks++) {
        const bf16x8 B = *(const bf16x8*)(wr + ks * 32 + quad * 8);
        acc = MFMA(pA[ks], B, acc);
      }
      const float pb = proj_b[n * 16 + l15];
#pragma unroll
      for (int r = 0; r < 4; r++)
        out[(size_t)(b * NN + q0 + m0 + quad * 4 + r) * CD + n * 16 + l15] =
            acc[r] + pb;
    }
  }
}

// ---------------------------------------------------------------------------
extern "C" void kernel_launch(void* const* d_in, const int* in_sizes, int n_in,
                              void* d_out, int out_size, void* d_ws,
                              size_t ws_size, hipStream_t stream) {
  const float* x = (const float*)d_in[0];
  const float* dw_w = (const float*)d_in[3];
  const float* dw_b = (const float*)d_in[4];
  const float* pw_w = (const float*)d_in[5];
  const float* pw_b = (const float*)d_in[6];
  const float* ln_g = (const float*)d_in[7];
  const float* ln_b = (const float*)d_in[8];
  const float* q_w = (const float*)d_in[9];
  const float* k_w = (const float*)d_in[10];
  const float* v_w = (const float*)d_in[11];
  const float* proj_w = (const float*)d_in[12];
  const float* proj_b = (const float*)d_in[13];
  float* out = (float*)d_out;

  u16* w = (u16*)d_ws;
  u16* kbp = w;                 // [6288][480]   = 3,018,240
  u16* vt = kbp + 3018240;      // [32*320][224] = 2,293,760
  u16* qwT = vt + 2293760;      // [400][320]    = 128,000
  u16* pwT = qwT + 128000;      // [320][320]    = 102,400
  u16* kvwT = pwT + 102400;     // [720][416]    = 299,520
  u16* pwc = kvwT + 299520;     // [400][320]    = 128,000
                                // total ~11.9 MB

  k_prep<<<512, 256, 0, stream>>>(q_w, proj_w, k_w, v_w, pw_w, qwT, pwT, kvwT,
                                  pwc);
  k_spkv<<<dim3(13, NB), 64, 0, stream>>>(x, dw_w, dw_b, pwc, pw_b, ln_g, ln_b,
                                          kvwT, kbp, vt);
  k_mega<<<dim3(98, NB), 128, 0, stream>>>(x, qwT, kbp, vt, pwT, proj_b, out);
}